// Round 13
// baseline (1111.920 us; speedup 1.0000x reference)
//
#include <hip/hip_runtime.h>
#include <math.h>

#define Bc 32
#define Tc 4096
#define Dc 768
#define Hc 1024
#define BTc (Bc*Tc)
#define PLANE 786432   // 96*1024*8 ushorts per split plane

typedef __bf16 bf16x8 __attribute__((ext_vector_type(8)));
typedef float f32x16 __attribute__((ext_vector_type(16)));

__device__ __forceinline__ float gelu_erf(float x) {
  return 0.5f * x * (1.0f + erff(x * 0.70710678118654752440f));
}
__device__ __forceinline__ unsigned bf16rne(float x) {
  unsigned u = __float_as_uint(x);
  return (u + 0x7FFFu + ((u >> 16) & 1u)) >> 16;
}
// exact 3-way bf16 split: x ~= hi+mid+lo, residual ~2^-27 |x|
__device__ __forceinline__ void split3(float x, unsigned& h, unsigned& m, unsigned& l) {
  h = bf16rne(x);
  float r1 = x - __uint_as_float(h << 16);
  m = bf16rne(r1);
  float r2 = r1 - __uint_as_float(m << 16);
  l = bf16rne(r2);
}
__device__ __forceinline__ unsigned f2o(float f) {
  unsigned b = __float_as_uint(f);
  return (b & 0x80000000u) ? ~b : (b | 0x80000000u);
}
__device__ __forceinline__ float o2f(unsigned o) {
  unsigned b = (o & 0x80000000u) ? (o & 0x7FFFFFFFu) : ~o;
  return __uint_as_float(b);
}

// ---------------- Kernel 0: pre-split W1 into 3 bf16 planes -----------------
__global__ __launch_bounds__(256) void w1_split_k(
    const float* __restrict__ W1, ushort* __restrict__ w1s) {
  int id = blockIdx.x * 256 + threadIdx.x;   // 96*1024 total
  int n = id & 1023, kg = id >> 10;
  unsigned hs[8], ms[8], ls[8];
  #pragma unroll
  for (int j = 0; j < 8; j++) {
    float x = W1[(size_t)(kg * 8 + j) * Hc + n];
    split3(x, hs[j], ms[j], ls[j]);
  }
  size_t o = ((size_t)kg * 1024 + n) * 8;
  int4 ph, pm, pl;
  ph.x = (int)(hs[0] | (hs[1] << 16)); ph.y = (int)(hs[2] | (hs[3] << 16));
  ph.z = (int)(hs[4] | (hs[5] << 16)); ph.w = (int)(hs[6] | (hs[7] << 16));
  pm.x = (int)(ms[0] | (ms[1] << 16)); pm.y = (int)(ms[2] | (ms[3] << 16));
  pm.z = (int)(ms[4] | (ms[5] << 16)); pm.w = (int)(ms[6] | (ms[7] << 16));
  pl.x = (int)(ls[0] | (ls[1] << 16)); pl.y = (int)(ls[2] | (ls[3] << 16));
  pl.z = (int)(ls[4] | (ls[5] << 16)); pl.w = (int)(ls[6] | (ls[7] << 16));
  *(int4*)(w1s + o)             = ph;
  *(int4*)(w1s + o + PLANE)     = pm;
  *(int4*)(w1s + o + 2 * PLANE) = pl;
}

// ---------------- Kernel 1: masked LayerNorm stats (mu, rstd per row) -------
__global__ __launch_bounds__(256) void ln_stats_k(
    const float* __restrict__ emb, const float* __restrict__ attn,
    float* __restrict__ mu, float* __restrict__ rstd) {
  int row = blockIdx.x * 4 + (threadIdx.x >> 6);
  int lane = threadIdx.x & 63;
  float a = attn[row];
  const float4* e = (const float4*)(emb + (size_t)row * Dc);
  float4 v0 = e[lane], v1 = e[lane + 64], v2 = e[lane + 128];
  float x[12] = {v0.x*a, v0.y*a, v0.z*a, v0.w*a,
                 v1.x*a, v1.y*a, v1.z*a, v1.w*a,
                 v2.x*a, v2.y*a, v2.z*a, v2.w*a};
  float s = 0.f;
  #pragma unroll
  for (int i = 0; i < 12; i++) s += x[i];
  #pragma unroll
  for (int o = 32; o; o >>= 1) s += __shfl_xor(s, o);
  float m = s / 768.0f;
  float q = 0.f;
  #pragma unroll
  for (int i = 0; i < 12; i++) { float d = x[i] - m; q += d * d; }
  #pragma unroll
  for (int o = 32; o; o >>= 1) q += __shfl_xor(q, o);
  float var = q / 768.0f;
  if (lane == 0) { mu[row] = m; rstd[row] = 1.0f / sqrtf(var + 1e-5f); }
}

// ---- Kernel 2: MFMA GEMM, 128-row M-tile x 256-col H-quarter. -------------
// 256 threads (4 waves), wave = 128 rows x 64 cols (acc[8]=128 AGPR) ->
// keeps r12's 8-MFMA-per-B-load reuse AND r10's 2-blocks/CU TLP (the two
// levers that each won). XCD-pinned quarter: 1.125 MB B working set per XCD
// L2. Per-acc K-order bit-identical to round 12.
__global__ __launch_bounds__(256, 2) void gemm_scores_mfma11(
    const float* __restrict__ emb, const float* __restrict__ attn,
    const float* __restrict__ ln_g, const float* __restrict__ ln_b,
    const ushort* __restrict__ w1s, const float* __restrict__ b1,
    const float* __restrict__ W2, const float* __restrict__ b2,
    const float* __restrict__ mu, const float* __restrict__ rstd,
    float* __restrict__ spart) {
  __shared__ int4 Abuf[2][3][4][128];   // 48 KB: [buf][split][kg][row] 16B
  __shared__ float gls[768], bls[768];  // 6 KB
  __shared__ float red[4][128];         // 2 KB
  const int id = blockIdx.x;
  const int xcd = id & 7;               // dispatch round-robins XCDs [m09]
  const int q = xcd & 3;                // XCD -> H-quarter (L2 pinning)
  const int mg = (id >> 3) * 2 + (xcd >> 2);   // 0..1023
  const int base = mg * 128;
  if (attn[base] == 0.0f) return;       // attn is a prefix mask
  const int hbase = q * 256;
  const int t = threadIdx.x;
  const int lane = t & 63;
  const int lrow = lane & 31;
  const int lkg = lane >> 5;
  const int w = t >> 6;                 // wave id = 64-col group 0..3

  if (t < 192) {
    *(float4*)&gls[t * 4] = *(const float4*)&ln_g[t * 4];
    *(float4*)&bls[t * 4] = *(const float4*)&ln_b[t * 4];
  }
  // staging identity: 256 threads cover 128 rows x 2 kg-pairs, 16 elems each;
  // wave-linear b128 writes (consecutive srow per wave) -> conflict-free.
  const int srow = t & 127;
  const int sci = t >> 7;               // 0..1; thread stages kg = sci, sci+2
  const float la  = attn[base + srow];
  const float lmu = mu[base + srow];
  const float lrs = rstd[base + srow];
  const float* erow = emb + (size_t)(base + srow) * Dc;

  f32x16 acc[8];                        // [rt][nt], rt=0..3, nt=0..1
  #pragma unroll
  for (int nt = 0; nt < 8; nt++)
    #pragma unroll
    for (int r = 0; r < 16; r++) acc[nt][r] = 0.f;

  __syncthreads();  // gls/bls visible
  // ---- prologue: stage k0=0 into buf 0 (2 x 8 elems/thread) ----
  #pragma unroll
  for (int ci = 0; ci < 2; ci++) {
    const int kg = sci + 2 * ci;
    const int ko = kg * 8;
    float4 e0 = *(const float4*)(erow + ko);
    float4 e1 = *(const float4*)(erow + ko + 4);
    float4 g0 = *(const float4*)&gls[ko];
    float4 g1 = *(const float4*)&gls[ko + 4];
    float4 q0 = *(const float4*)&bls[ko];
    float4 q1 = *(const float4*)&bls[ko + 4];
    float xs[8] = {e0.x,e0.y,e0.z,e0.w,e1.x,e1.y,e1.z,e1.w};
    float gs[8] = {g0.x,g0.y,g0.z,g0.w,g1.x,g1.y,g1.z,g1.w};
    float bs[8] = {q0.x,q0.y,q0.z,q0.w,q1.x,q1.y,q1.z,q1.w};
    unsigned hh[8], hm[8], hl[8];
    #pragma unroll
    for (int e = 0; e < 8; e++) {
      float xn = (xs[e] * la - lmu) * lrs * gs[e] + bs[e];
      split3(xn, hh[e], hm[e], hl[e]);
    }
    int4 ph, pm, pl;
    ph.x = (int)(hh[0] | (hh[1] << 16)); ph.y = (int)(hh[2] | (hh[3] << 16));
    ph.z = (int)(hh[4] | (hh[5] << 16)); ph.w = (int)(hh[6] | (hh[7] << 16));
    pm.x = (int)(hm[0] | (hm[1] << 16)); pm.y = (int)(hm[2] | (hm[3] << 16));
    pm.z = (int)(hm[4] | (hm[5] << 16)); pm.w = (int)(hm[6] | (hm[7] << 16));
    pl.x = (int)(hl[0] | (hl[1] << 16)); pl.y = (int)(hl[2] | (hl[3] << 16));
    pl.z = (int)(hl[4] | (hl[5] << 16)); pl.w = (int)(hl[6] | (hl[7] << 16));
    Abuf[0][0][kg][srow] = ph;
    Abuf[0][1][kg][srow] = pm;
    Abuf[0][2][kg][srow] = pl;
  }
  __syncthreads();

  // per-lane B base: col = hbase + w*64 + nt*32 + lrow; kg offset via lkg
  const ushort* wbase = w1s + ((size_t)hbase + w * 64 + lrow) * 8;

  #pragma unroll 1
  for (int i = 0; i < 24; i++) {
    const int p = i & 1;
    const bool more = (i < 23);
    #pragma unroll
    for (int kh = 0; kh < 2; kh++) {
      const int kg = kh * 2 + lkg;
      const ushort* bp = wbase + (size_t)(i * 4 + kg) * 8192;
      bf16x8 Bh0 = *(const bf16x8*)(bp);
      bf16x8 Bh1 = *(const bf16x8*)(bp + 256);
      bf16x8 Bm0 = *(const bf16x8*)(bp + PLANE);
      bf16x8 Bm1 = *(const bf16x8*)(bp + PLANE + 256);
      bf16x8 Bl0 = *(const bf16x8*)(bp + 2 * PLANE);
      bf16x8 Bl1 = *(const bf16x8*)(bp + 2 * PLANE + 256);
      #pragma unroll
      for (int rt = 0; rt < 4; rt++) {
        bf16x8 a0 = *(const bf16x8*)&Abuf[p][0][kg][rt * 32 + lrow];
        bf16x8 a1 = *(const bf16x8*)&Abuf[p][1][kg][rt * 32 + lrow];
        bf16x8 a2 = *(const bf16x8*)&Abuf[p][2][kg][rt * 32 + lrow];
        f32x16* ac = acc + rt * 2;
        // per-acc order hh,hm,mh,mm,hl,lh — identical to round 12
        ac[0] = __builtin_amdgcn_mfma_f32_32x32x16_bf16(a0, Bh0, ac[0], 0, 0, 0);
        ac[1] = __builtin_amdgcn_mfma_f32_32x32x16_bf16(a0, Bh1, ac[1], 0, 0, 0);
        ac[0] = __builtin_amdgcn_mfma_f32_32x32x16_bf16(a0, Bm0, ac[0], 0, 0, 0);
        ac[1] = __builtin_amdgcn_mfma_f32_32x32x16_bf16(a0, Bm1, ac[1], 0, 0, 0);
        ac[0] = __builtin_amdgcn_mfma_f32_32x32x16_bf16(a1, Bh0, ac[0], 0, 0, 0);
        ac[1] = __builtin_amdgcn_mfma_f32_32x32x16_bf16(a1, Bh1, ac[1], 0, 0, 0);
        ac[0] = __builtin_amdgcn_mfma_f32_32x32x16_bf16(a1, Bm0, ac[0], 0, 0, 0);
        ac[1] = __builtin_amdgcn_mfma_f32_32x32x16_bf16(a1, Bm1, ac[1], 0, 0, 0);
        ac[0] = __builtin_amdgcn_mfma_f32_32x32x16_bf16(a0, Bl0, ac[0], 0, 0, 0);
        ac[1] = __builtin_amdgcn_mfma_f32_32x32x16_bf16(a0, Bl1, ac[1], 0, 0, 0);
        ac[0] = __builtin_amdgcn_mfma_f32_32x32x16_bf16(a2, Bh0, ac[0], 0, 0, 0);
        ac[1] = __builtin_amdgcn_mfma_f32_32x32x16_bf16(a2, Bh1, ac[1], 0, 0, 0);
      }
    }
    if (more) {
      #pragma unroll
      for (int ci = 0; ci < 2; ci++) {
        const int kg = sci + 2 * ci;
        const int ko = (i + 1) * 32 + kg * 8;
        float4 e0 = *(const float4*)(erow + ko);
        float4 e1 = *(const float4*)(erow + ko + 4);
        float4 g0 = *(const float4*)&gls[ko];
        float4 g1 = *(const float4*)&gls[ko + 4];
        float4 q0 = *(const float4*)&bls[ko];
        float4 q1 = *(const float4*)&bls[ko + 4];
        float xs[8] = {e0.x,e0.y,e0.z,e0.w,e1.x,e1.y,e1.z,e1.w};
        float gs[8] = {g0.x,g0.y,g0.z,g0.w,g1.x,g1.y,g1.z,g1.w};
        float bs[8] = {q0.x,q0.y,q0.z,q0.w,q1.x,q1.y,q1.z,q1.w};
        unsigned hh[8], hm[8], hl[8];
        #pragma unroll
        for (int e = 0; e < 8; e++) {
          float xn = (xs[e] * la - lmu) * lrs * gs[e] + bs[e];
          split3(xn, hh[e], hm[e], hl[e]);
        }
        int4 ph, pm, pl;
        ph.x = (int)(hh[0] | (hh[1] << 16)); ph.y = (int)(hh[2] | (hh[3] << 16));
        ph.z = (int)(hh[4] | (hh[5] << 16)); ph.w = (int)(hh[6] | (hh[7] << 16));
        pm.x = (int)(hm[0] | (hm[1] << 16)); pm.y = (int)(hm[2] | (hm[3] << 16));
        pm.z = (int)(hm[4] | (hm[5] << 16)); pm.w = (int)(hm[6] | (hm[7] << 16));
        pl.x = (int)(hl[0] | (hl[1] << 16)); pl.y = (int)(hl[2] | (hl[3] << 16));
        pl.z = (int)(hl[4] | (hl[5] << 16)); pl.w = (int)(hl[6] | (hl[7] << 16));
        Abuf[p ^ 1][0][kg][srow] = ph;
        Abuf[p ^ 1][1][kg][srow] = pm;
        Abuf[p ^ 1][2][kg][srow] = pl;
      }
    }
    __syncthreads();
  }

  // ---- epilogue: bias + erf-gelu + W2 dot; red[w] = wave's 64-col partial --
  #pragma unroll
  for (int rt = 0; rt < 4; rt++) {
    float sacc[16];
    #pragma unroll
    for (int r = 0; r < 16; r++) sacc[r] = 0.f;
    #pragma unroll
    for (int nt = 0; nt < 2; nt++) {
      const int col = hbase + w * 64 + nt * 32 + lrow;
      const float b1v = b1[col];
      const float w2v = W2[col];
      #pragma unroll
      for (int r = 0; r < 16; r++)
        sacc[r] += gelu_erf(acc[rt * 2 + nt][r] + b1v) * w2v;
    }
    #pragma unroll
    for (int r = 0; r < 16; r++) {
      float v = sacc[r];
      v += __shfl_xor(v, 1);  v += __shfl_xor(v, 2);  v += __shfl_xor(v, 4);
      v += __shfl_xor(v, 8);  v += __shfl_xor(v, 16);
      if (lrow == 0) {
        int row = rt * 32 + (r & 3) + 8 * (r >> 2) + 4 * lkg;
        red[w][row] = v;
      }
    }
  }
  __syncthreads();
  if (t < 128) {
    float v = red[0][t] + red[1][t] + red[2][t] + red[3][t];
    if (q == 0) v += b2[0];
    spart[q * BTc + base + t] = v;
  }
}

// ---- Kernel 3: 1.5-entmax (f64 tau), exact stable ranking, h-mask writes ---
__global__ __launch_bounds__(256) void entmax_rank_k(
    const float* __restrict__ sp0, const float* __restrict__ sp1,
    const float* __restrict__ sp2, const float* __restrict__ sp3,
    const float* __restrict__ attn, float* __restrict__ out) {
  const int N = 4096;
  __shared__ unsigned long long keys[4096];
  __shared__ double tsum[256], tsq[256];
  __shared__ int tcnt[256];
  __shared__ float sred[4];
  __shared__ double sh_tau;
  __shared__ int sh_S, sh_m, sh_k[5];
  const int b = blockIdx.x;
  const int t = threadIdx.x;
  const float* srow0 = sp0 + b * N;
  const float* srow1 = sp1 + b * N;
  const float* srow2 = sp2 + b * N;
  const float* srow3 = sp3 + b * N;
  const float* arow = attn + b * N;
  float teff_l = 0.f;
  for (int i = t; i < N; i += 256) {
    float a = arow[i];
    float s = srow0[i] + srow1[i] + srow2[i] + srow3[i];
    float xe = (a == 0.f) ? -1e9f : s;
    teff_l += a;
    keys[i] = ((unsigned long long)f2o(xe) << 32) |
              (unsigned long long)(0xFFFFFFFFu - (unsigned)i);
  }
  #pragma unroll
  for (int o = 32; o; o >>= 1) teff_l += __shfl_xor(teff_l, o);
  if ((t & 63) == 0) sred[t >> 6] = teff_l;
  __syncthreads();
  if (t == 0) {
    float te = sred[0] + sred[1] + sred[2] + sred[3];
    const float rh[5] = {0.1f, 0.3f, 0.5f, 0.7f, 0.9f};
    for (int r = 0; r < 5; r++) {
      int ki = (int)floorf(rh[r] * te);   // must be f32 math
      sh_k[r] = ki < 1 ? 1 : ki;
    }
  }
  for (int kk = 2; kk <= N; kk <<= 1) {
    for (int j = kk >> 1; j > 0; j >>= 1) {
      __syncthreads();
      for (int idx = t; idx < N / 2; idx += 256) {
        int i = 2 * idx - (idx & (j - 1));
        int l = i | j;
        unsigned long long A = keys[i], Bv = keys[l];
        bool up = ((i & kk) == 0);
        if (up ? (A < Bv) : (A > Bv)) { keys[i] = Bv; keys[l] = A; }
      }
    }
  }
  __syncthreads();
  const int base = t * 16;
  {
    double ls = 0, lq = 0;
    for (int ii = 0; ii < 16; ii++) {
      double x = 0.5 * (double)o2f((unsigned)(keys[base + ii] >> 32));
      ls += x; lq += x * x;
    }
    tsum[t] = ls; tsq[t] = lq;
  }
  __syncthreads();
  if (t == 0) {
    double rs = 0, rq = 0;
    for (int i = 0; i < 256; i++) {
      double a = tsum[i], c = tsq[i];
      tsum[i] = rs; tsq[i] = rq; rs += a; rq += c;
    }
  }
  __syncthreads();
  {
    double cs = tsum[t], cq = tsq[t];
    int lc = 0;
    for (int ii = 0; ii < 16; ii++) {
      double x = 0.5 * (double)o2f((unsigned)(keys[base + ii] >> 32));
      cs += x; cq += x * x;
      double rho = (double)(base + ii + 1);
      double mean = cs / rho, msq = cq / rho;
      double ss = rho * (msq - mean * mean);
      double delta = (1.0 - ss) / rho;
      double dl = delta > 0.0 ? delta : 0.0;
      double tau = mean - sqrt(dl);
      if (tau <= x) lc++;
    }
    tcnt[t] = lc;
  }
  __syncthreads();
  if (t == 0) {
    int r = 0;
    for (int i = 0; i < 256; i++) { int c = tcnt[i]; tcnt[i] = r; r += c; }
    sh_S = r;
  }
  __syncthreads();
  {
    int jstar = sh_S - 1;
    if (jstar >= base && jstar < base + 16) {
      double cs = tsum[t], cq = tsq[t], tau = 0.0;
      for (int ii = 0; ii <= jstar - base; ii++) {
        double x = 0.5 * (double)o2f((unsigned)(keys[base + ii] >> 32));
        cs += x; cq += x * x;
        double rho = (double)(base + ii + 1);
        double mean = cs / rho, msq = cq / rho;
        double ss = rho * (msq - mean * mean);
        double delta = (1.0 - ss) / rho;
        double dl = delta > 0.0 ? delta : 0.0;
        tau = mean - sqrt(dl);
      }
      sh_tau = tau;
    }
  }
  __syncthreads();
  const double tau = sh_tau;
  float ps[16], pa[16];
  {
    int lf = 0;
    for (int ii = 0; ii < 16; ii++) {
      int p = base + ii;
      ps[ii] = srow0[p] + srow1[p] + srow2[p] + srow3[p];
      pa[ii] = arow[p];
      double d = 0.5 * (double)ps[ii] - tau;
      if (pa[ii] != 0.f && d > 0.0) lf++;
    }
    tcnt[t] = lf;
  }
  __syncthreads();
  if (t == 0) {
    int r = 0;
    for (int i = 0; i < 256; i++) { int c = tcnt[i]; tcnt[i] = r; r += c; }
    sh_m = r;
  }
  __syncthreads();
  const int m = sh_m;
  const int k0_ = sh_k[0], k1_ = sh_k[1], k2_ = sh_k[2], k3_ = sh_k[3], k4_ = sh_k[4];
  {
    int cex = tcnt[t];
    for (int ii = 0; ii < 16; ii++) {
      int p = base + ii;
      double d = 0.5 * (double)ps[ii] - tau;
      bool av = (pa[ii] != 0.f);
      bool sup = av && (d > 0.0);
      out[b * N + p] = sup ? (float)(d * d) : 0.0f;
      if (!sup) {
        int rank = m + p - cex;
        out[1 * BTc + b * N + p] = (av && rank < k0_) ? 1.f : 0.f;
        out[2 * BTc + b * N + p] = (av && rank < k1_) ? 1.f : 0.f;
        out[3 * BTc + b * N + p] = (av && rank < k2_) ? 1.f : 0.f;
        out[4 * BTc + b * N + p] = (av && rank < k3_) ? 1.f : 0.f;
        out[5 * BTc + b * N + p] = (av && rank < k4_) ? 1.f : 0.f;
      } else {
        cex++;
      }
    }
  }
  for (int r = t; r < m; r += 256) {
    int i = (int)(0xFFFFFFFFu - (unsigned)(keys[r] & 0xFFFFFFFFull));
    out[1 * BTc + b * N + i] = (r < k0_) ? 1.f : 0.f;
    out[2 * BTc + b * N + i] = (r < k1_) ? 1.f : 0.f;
    out[3 * BTc + b * N + i] = (r < k2_) ? 1.f : 0.f;
    out[4 * BTc + b * N + i] = (r < k3_) ? 1.f : 0.f;
    out[5 * BTc + b * N + i] = (r < k4_) ? 1.f : 0.f;
  }
}

extern "C" void kernel_launch(void* const* d_in, const int* in_sizes, int n_in,
                              void* d_out, int out_size, void* d_ws, size_t ws_size,
                              hipStream_t stream) {
  (void)in_sizes; (void)n_in; (void)out_size; (void)ws_size;
  const float* emb  = (const float*)d_in[0];
  const float* attn = (const float*)d_in[1];
  const float* ln_g = (const float*)d_in[2];
  const float* ln_b = (const float*)d_in[3];
  const float* W1   = (const float*)d_in[4];
  const float* b1   = (const float*)d_in[5];
  const float* W2   = (const float*)d_in[6];
  const float* b2   = (const float*)d_in[7];
  float* out = (float*)d_out;
  float* wsf = (float*)d_ws;
  float* mu     = wsf;
  float* rstd   = wsf + BTc;
  float* spart  = wsf + 2 * BTc;             // [4][BTc]
  ushort* w1s   = (ushort*)(wsf + 6 * BTc);  // 3 planes * 1.5 MB

  w1_split_k<<<384, 256, 0, stream>>>(W1, w1s);
  ln_stats_k<<<BTc / 4, 256, 0, stream>>>(emb, attn, mu, rstd);
  gemm_scores_mfma11<<<4096, 256, 0, stream>>>(
      emb, attn, ln_g, ln_b, w1s, b1, W2, b2, mu, rstd, spart);
  entmax_rank_k<<<Bc, 256, 0, stream>>>(
      spart, spart + BTc, spart + 2 * BTc, spart + 3 * BTc, attn, out);
}

// Round 14
// 952.512 us; speedup vs baseline: 1.1674x; 1.1674x over previous
//
#include <hip/hip_runtime.h>
#include <math.h>

#define Bc 32
#define Tc 4096
#define Dc 768
#define Hc 1024
#define BTc (Bc*Tc)
#define PLANE 786432   // 96*1024*8 ushorts per split plane

typedef __bf16 bf16x8 __attribute__((ext_vector_type(8)));
typedef float f32x16 __attribute__((ext_vector_type(16)));

__device__ __forceinline__ float gelu_erf(float x) {
  return 0.5f * x * (1.0f + erff(x * 0.70710678118654752440f));
}
__device__ __forceinline__ unsigned bf16rne(float x) {
  unsigned u = __float_as_uint(x);
  return (u + 0x7FFFu + ((u >> 16) & 1u)) >> 16;
}
// exact 3-way bf16 split: x ~= hi+mid+lo, residual ~2^-27 |x|
__device__ __forceinline__ void split3(float x, unsigned& h, unsigned& m, unsigned& l) {
  h = bf16rne(x);
  float r1 = x - __uint_as_float(h << 16);
  m = bf16rne(r1);
  float r2 = r1 - __uint_as_float(m << 16);
  l = bf16rne(r2);
}
__device__ __forceinline__ unsigned f2o(float f) {
  unsigned b = __float_as_uint(f);
  return (b & 0x80000000u) ? ~b : (b | 0x80000000u);
}
__device__ __forceinline__ float o2f(unsigned o) {
  unsigned b = (o & 0x80000000u) ? (o & 0x7FFFFFFFu) : ~o;
  return __uint_as_float(b);
}

// B-fragment register block: 4 N-tiles of one k-group (12 x 16B = 48 VGPRs)
struct Bfrag { bf16x8 h[4], m[4], l[4]; };

__device__ __forceinline__ void loadB(const ushort* __restrict__ bp0, Bfrag& B) {
  #pragma unroll
  for (int nt = 0; nt < 4; nt++) {
    const ushort* bp = bp0 + nt * 256;     // 32 cols * 8
    B.h[nt] = *(const bf16x8*)(bp);
    B.m[nt] = *(const bf16x8*)(bp + PLANE);
    B.l[nt] = *(const bf16x8*)(bp + 2 * PLANE);
  }
}

// pass-outer / nt-inner; per-acc order (hh,hm,mh,mm,hl,lh) UNCHANGED.
__device__ __forceinline__ void mfma6(bf16x8 a0, bf16x8 a1, bf16x8 a2,
                                      const Bfrag& B, f32x16* acc) {
  #pragma unroll
  for (int nt = 0; nt < 4; nt++)
    acc[nt] = __builtin_amdgcn_mfma_f32_32x32x16_bf16(a0, B.h[nt], acc[nt], 0, 0, 0);
  #pragma unroll
  for (int nt = 0; nt < 4; nt++)
    acc[nt] = __builtin_amdgcn_mfma_f32_32x32x16_bf16(a0, B.m[nt], acc[nt], 0, 0, 0);
  #pragma unroll
  for (int nt = 0; nt < 4; nt++)
    acc[nt] = __builtin_amdgcn_mfma_f32_32x32x16_bf16(a1, B.h[nt], acc[nt], 0, 0, 0);
  #pragma unroll
  for (int nt = 0; nt < 4; nt++)
    acc[nt] = __builtin_amdgcn_mfma_f32_32x32x16_bf16(a1, B.m[nt], acc[nt], 0, 0, 0);
  #pragma unroll
  for (int nt = 0; nt < 4; nt++)
    acc[nt] = __builtin_amdgcn_mfma_f32_32x32x16_bf16(a0, B.l[nt], acc[nt], 0, 0, 0);
  #pragma unroll
  for (int nt = 0; nt < 4; nt++)
    acc[nt] = __builtin_amdgcn_mfma_f32_32x32x16_bf16(a2, B.h[nt], acc[nt], 0, 0, 0);
}

// ---------------- Kernel 0: pre-split W1 into 3 bf16 planes -----------------
__global__ __launch_bounds__(256) void w1_split_k(
    const float* __restrict__ W1, ushort* __restrict__ w1s) {
  int id = blockIdx.x * 256 + threadIdx.x;   // 96*1024 total
  int n = id & 1023, kg = id >> 10;
  unsigned hs[8], ms[8], ls[8];
  #pragma unroll
  for (int j = 0; j < 8; j++) {
    float x = W1[(size_t)(kg * 8 + j) * Hc + n];
    split3(x, hs[j], ms[j], ls[j]);
  }
  size_t o = ((size_t)kg * 1024 + n) * 8;
  int4 ph, pm, pl;
  ph.x = (int)(hs[0] | (hs[1] << 16)); ph.y = (int)(hs[2] | (hs[3] << 16));
  ph.z = (int)(hs[4] | (hs[5] << 16)); ph.w = (int)(hs[6] | (hs[7] << 16));
  pm.x = (int)(ms[0] | (ms[1] << 16)); pm.y = (int)(ms[2] | (ms[3] << 16));
  pm.z = (int)(ms[4] | (ms[5] << 16)); pm.w = (int)(ms[6] | (ms[7] << 16));
  pl.x = (int)(ls[0] | (ls[1] << 16)); pl.y = (int)(ls[2] | (ls[3] << 16));
  pl.z = (int)(ls[4] | (ls[5] << 16)); pl.w = (int)(ls[6] | (ls[7] << 16));
  *(int4*)(w1s + o)             = ph;
  *(int4*)(w1s + o + PLANE)     = pm;
  *(int4*)(w1s + o + 2 * PLANE) = pl;
}

// ---------------- Kernel 1: masked LayerNorm stats (mu, rstd per row) -------
__global__ __launch_bounds__(256) void ln_stats_k(
    const float* __restrict__ emb, const float* __restrict__ attn,
    float* __restrict__ mu, float* __restrict__ rstd) {
  int row = blockIdx.x * 4 + (threadIdx.x >> 6);
  int lane = threadIdx.x & 63;
  float a = attn[row];
  const float4* e = (const float4*)(emb + (size_t)row * Dc);
  float4 v0 = e[lane], v1 = e[lane + 64], v2 = e[lane + 128];
  float x[12] = {v0.x*a, v0.y*a, v0.z*a, v0.w*a,
                 v1.x*a, v1.y*a, v1.z*a, v1.w*a,
                 v2.x*a, v2.y*a, v2.z*a, v2.w*a};
  float s = 0.f;
  #pragma unroll
  for (int i = 0; i < 12; i++) s += x[i];
  #pragma unroll
  for (int o = 32; o; o >>= 1) s += __shfl_xor(s, o);
  float m = s / 768.0f;
  float q = 0.f;
  #pragma unroll
  for (int i = 0; i < 12; i++) { float d = x[i] - m; q += d * d; }
  #pragma unroll
  for (int o = 32; o; o >>= 1) q += __shfl_xor(q, o);
  float var = q / 768.0f;
  if (lane == 0) { mu[row] = m; rstd[row] = 1.0f / sqrtf(var + 1e-5f); }
}

// ---- Kernel 2: r10 structure + BK=64 (half the barriers per MFMA). --------
// Block 64 rows x 512 cols (XCD-pinned H-half), 4 waves, wave = 64x128
// (2 rt x 4 nt, acc[8]=128 AGPR), 2 blocks/CU (LDS 55KB, regs ~232 unified).
// 12 K-iters x 192 MFMAs between barriers (was 24 x 96). Flattened per-lane
// kgg order {8i+2kh+lkg} == r10's {4i+2kh+lkg}: scores BIT-IDENTICAL to r10.
__global__ __launch_bounds__(256, 2) void gemm_scores_mfma12(
    const float* __restrict__ emb, const float* __restrict__ attn,
    const float* __restrict__ ln_g, const float* __restrict__ ln_b,
    const ushort* __restrict__ w1s, const float* __restrict__ b1,
    const float* __restrict__ W2, const float* __restrict__ b2,
    const float* __restrict__ mu, const float* __restrict__ rstd,
    float* __restrict__ spart) {
  __shared__ int4 Abuf[2][3][8][64];    // 48 KB: [buf][split][kg][row] 16B
  __shared__ float gls[768], bls[768];  // 6 KB
  __shared__ float red[4][64];          // 1 KB
  const int id = blockIdx.x;
  const int xcd = id & 7;               // dispatch round-robins XCDs [m09]
  const int y = xcd & 1;                // XCD parity -> H-half (L2 pinning)
  const int xg = (id >> 3) * 4 + (xcd >> 1);   // 0..2047
  const int base = xg * 64;
  if (attn[base] == 0.0f) return;       // attn is a prefix mask
  const int hbase = y * 512;
  const int t = threadIdx.x;
  const int lane = t & 63;
  const int lrow = lane & 31;
  const int lkg = lane >> 5;
  const int w = t >> 6;                 // wave id = 128-col group 0..3

  if (t < 192) {
    *(float4*)&gls[t * 4] = *(const float4*)&ln_g[t * 4];
    *(float4*)&bls[t * 4] = *(const float4*)&ln_b[t * 4];
  }
  // staging identity: 256 threads cover 64 rows x 8 kg (2 chunks each);
  // srow = lane -> wave-linear b128 writes, conflict-free (r10 pattern).
  const int srow = t & 63;
  const int sci = t >> 6;               // 0..3; thread stages kg = sci, sci+4
  const float la  = attn[base + srow];
  const float lmu = mu[base + srow];
  const float lrs = rstd[base + srow];
  const float* erow = emb + (size_t)(base + srow) * Dc;

  f32x16 acc[8];                        // [rt][nt]
  #pragma unroll
  for (int nt = 0; nt < 8; nt++)
    #pragma unroll
    for (int r = 0; r < 16; r++) acc[nt][r] = 0.f;

  __syncthreads();  // gls/bls visible
  // ---- prologue: stage k0=0..63 into buf 0 (2 x 8 elems/thread) ----
  #pragma unroll
  for (int ci = 0; ci < 2; ci++) {
    const int kg = sci + 4 * ci;
    const int ko = kg * 8;
    float4 e0 = *(const float4*)(erow + ko);
    float4 e1 = *(const float4*)(erow + ko + 4);
    float4 g0 = *(const float4*)&gls[ko];
    float4 g1 = *(const float4*)&gls[ko + 4];
    float4 q0 = *(const float4*)&bls[ko];
    float4 q1 = *(const float4*)&bls[ko + 4];
    float xs[8] = {e0.x,e0.y,e0.z,e0.w,e1.x,e1.y,e1.z,e1.w};
    float gs[8] = {g0.x,g0.y,g0.z,g0.w,g1.x,g1.y,g1.z,g1.w};
    float bs[8] = {q0.x,q0.y,q0.z,q0.w,q1.x,q1.y,q1.z,q1.w};
    unsigned hh[8], hm[8], hl[8];
    #pragma unroll
    for (int e = 0; e < 8; e++) {
      float xn = (xs[e] * la - lmu) * lrs * gs[e] + bs[e];
      split3(xn, hh[e], hm[e], hl[e]);
    }
    int4 ph, pm, pl;
    ph.x = (int)(hh[0] | (hh[1] << 16)); ph.y = (int)(hh[2] | (hh[3] << 16));
    ph.z = (int)(hh[4] | (hh[5] << 16)); ph.w = (int)(hh[6] | (hh[7] << 16));
    pm.x = (int)(hm[0] | (hm[1] << 16)); pm.y = (int)(hm[2] | (hm[3] << 16));
    pm.z = (int)(hm[4] | (hm[5] << 16)); pm.w = (int)(hm[6] | (hm[7] << 16));
    pl.x = (int)(hl[0] | (hl[1] << 16)); pl.y = (int)(hl[2] | (hl[3] << 16));
    pl.z = (int)(hl[4] | (hl[5] << 16)); pl.w = (int)(hl[6] | (hl[7] << 16));
    Abuf[0][0][kg][srow] = ph;
    Abuf[0][1][kg][srow] = pm;
    Abuf[0][2][kg][srow] = pl;
  }
  __syncthreads();

  // per-lane B base: col = hbase + w*128 + nt*32 + lrow
  const ushort* wbase = w1s + ((size_t)hbase + w * 128 + lrow) * 8;

  #pragma unroll 1
  for (int i = 0; i < 12; i++) {
    const int p = i & 1;
    const bool more = (i < 11);
    #pragma unroll
    for (int kh = 0; kh < 4; kh++) {
      const int kg = kh * 2 + lkg;
      bf16x8 a00 = *(const bf16x8*)&Abuf[p][0][kg][lrow];        // rt=0
      bf16x8 a01 = *(const bf16x8*)&Abuf[p][1][kg][lrow];
      bf16x8 a02 = *(const bf16x8*)&Abuf[p][2][kg][lrow];
      bf16x8 a10 = *(const bf16x8*)&Abuf[p][0][kg][32 + lrow];   // rt=1
      bf16x8 a11 = *(const bf16x8*)&Abuf[p][1][kg][32 + lrow];
      bf16x8 a12 = *(const bf16x8*)&Abuf[p][2][kg][32 + lrow];
      Bfrag B;
      loadB(wbase + (size_t)(i * 8 + kg) * 8192, B);
      mfma6(a00, a01, a02, B, acc);       // rows 0-31
      mfma6(a10, a11, a12, B, acc + 4);   // rows 32-63 (B reused from regs)
    }
    if (more) {
      #pragma unroll
      for (int ci = 0; ci < 2; ci++) {
        const int kg = sci + 4 * ci;
        const int ko = (i + 1) * 64 + kg * 8;
        float4 e0 = *(const float4*)(erow + ko);
        float4 e1 = *(const float4*)(erow + ko + 4);
        float4 g0 = *(const float4*)&gls[ko];
        float4 g1 = *(const float4*)&gls[ko + 4];
        float4 q0 = *(const float4*)&bls[ko];
        float4 q1 = *(const float4*)&bls[ko + 4];
        float xs[8] = {e0.x,e0.y,e0.z,e0.w,e1.x,e1.y,e1.z,e1.w};
        float gs[8] = {g0.x,g0.y,g0.z,g0.w,g1.x,g1.y,g1.z,g1.w};
        float bs[8] = {q0.x,q0.y,q0.z,q0.w,q1.x,q1.y,q1.z,q1.w};
        unsigned hh[8], hm[8], hl[8];
        #pragma unroll
        for (int e = 0; e < 8; e++) {
          float xn = (xs[e] * la - lmu) * lrs * gs[e] + bs[e];
          split3(xn, hh[e], hm[e], hl[e]);
        }
        int4 ph, pm, pl;
        ph.x = (int)(hh[0] | (hh[1] << 16)); ph.y = (int)(hh[2] | (hh[3] << 16));
        ph.z = (int)(hh[4] | (hh[5] << 16)); ph.w = (int)(hh[6] | (hh[7] << 16));
        pm.x = (int)(hm[0] | (hm[1] << 16)); pm.y = (int)(hm[2] | (hm[3] << 16));
        pm.z = (int)(hm[4] | (hm[5] << 16)); pm.w = (int)(hm[6] | (hm[7] << 16));
        pl.x = (int)(hl[0] | (hl[1] << 16)); pl.y = (int)(hl[2] | (hl[3] << 16));
        pl.z = (int)(hl[4] | (hl[5] << 16)); pl.w = (int)(hl[6] | (hl[7] << 16));
        Abuf[p ^ 1][0][kg][srow] = ph;
        Abuf[p ^ 1][1][kg][srow] = pm;
        Abuf[p ^ 1][2][kg][srow] = pl;
      }
    }
    __syncthreads();
  }

  // ---- epilogue: bias + erf-gelu + W2 dot (identical to round 10) ---------
  #pragma unroll
  for (int rt = 0; rt < 2; rt++) {
    float sacc[16];
    #pragma unroll
    for (int r = 0; r < 16; r++) sacc[r] = 0.f;
    #pragma unroll
    for (int nt = 0; nt < 4; nt++) {
      const int col = hbase + w * 128 + nt * 32 + lrow;
      const float b1v = b1[col];
      const float w2v = W2[col];
      #pragma unroll
      for (int r = 0; r < 16; r++)
        sacc[r] += gelu_erf(acc[rt * 4 + nt][r] + b1v) * w2v;
    }
    #pragma unroll
    for (int r = 0; r < 16; r++) {
      float v = sacc[r];
      v += __shfl_xor(v, 1);  v += __shfl_xor(v, 2);  v += __shfl_xor(v, 4);
      v += __shfl_xor(v, 8);  v += __shfl_xor(v, 16);
      if (lrow == 0) {
        int row = rt * 32 + (r & 3) + 8 * (r >> 2) + 4 * lkg;
        red[w][row] = v;
      }
    }
  }
  __syncthreads();
  if (t < 64) {
    float v = red[0][t] + red[1][t] + red[2][t] + red[3][t];
    if (y == 0) v += b2[0];
    spart[y * BTc + base + t] = v;
  }
}

// ---- Kernel 3: 1.5-entmax (f64 tau), exact stable ranking, h-mask writes ---
__global__ __launch_bounds__(256) void entmax_rank_k(
    const float* __restrict__ sp0, const float* __restrict__ sp1,
    const float* __restrict__ attn, float* __restrict__ out) {
  const int N = 4096;
  __shared__ unsigned long long keys[4096];
  __shared__ double tsum[256], tsq[256];
  __shared__ int tcnt[256];
  __shared__ float sred[4];
  __shared__ double sh_tau;
  __shared__ int sh_S, sh_m, sh_k[5];
  const int b = blockIdx.x;
  const int t = threadIdx.x;
  const float* srow0 = sp0 + b * N;
  const float* srow1 = sp1 + b * N;
  const float* arow = attn + b * N;
  float teff_l = 0.f;
  for (int i = t; i < N; i += 256) {
    float a = arow[i];
    float s = srow0[i] + srow1[i];
    float xe = (a == 0.f) ? -1e9f : s;
    teff_l += a;
    keys[i] = ((unsigned long long)f2o(xe) << 32) |
              (unsigned long long)(0xFFFFFFFFu - (unsigned)i);
  }
  #pragma unroll
  for (int o = 32; o; o >>= 1) teff_l += __shfl_xor(teff_l, o);
  if ((t & 63) == 0) sred[t >> 6] = teff_l;
  __syncthreads();
  if (t == 0) {
    float te = sred[0] + sred[1] + sred[2] + sred[3];
    const float rh[5] = {0.1f, 0.3f, 0.5f, 0.7f, 0.9f};
    for (int r = 0; r < 5; r++) {
      int ki = (int)floorf(rh[r] * te);   // must be f32 math
      sh_k[r] = ki < 1 ? 1 : ki;
    }
  }
  for (int kk = 2; kk <= N; kk <<= 1) {
    for (int j = kk >> 1; j > 0; j >>= 1) {
      __syncthreads();
      for (int idx = t; idx < N / 2; idx += 256) {
        int i = 2 * idx - (idx & (j - 1));
        int l = i | j;
        unsigned long long A = keys[i], Bv = keys[l];
        bool up = ((i & kk) == 0);
        if (up ? (A < Bv) : (A > Bv)) { keys[i] = Bv; keys[l] = A; }
      }
    }
  }
  __syncthreads();
  const int base = t * 16;
  {
    double ls = 0, lq = 0;
    for (int ii = 0; ii < 16; ii++) {
      double x = 0.5 * (double)o2f((unsigned)(keys[base + ii] >> 32));
      ls += x; lq += x * x;
    }
    tsum[t] = ls; tsq[t] = lq;
  }
  __syncthreads();
  if (t == 0) {
    double rs = 0, rq = 0;
    for (int i = 0; i < 256; i++) {
      double a = tsum[i], c = tsq[i];
      tsum[i] = rs; tsq[i] = rq; rs += a; rq += c;
    }
  }
  __syncthreads();
  {
    double cs = tsum[t], cq = tsq[t];
    int lc = 0;
    for (int ii = 0; ii < 16; ii++) {
      double x = 0.5 * (double)o2f((unsigned)(keys[base + ii] >> 32));
      cs += x; cq += x * x;
      double rho = (double)(base + ii + 1);
      double mean = cs / rho, msq = cq / rho;
      double ss = rho * (msq - mean * mean);
      double delta = (1.0 - ss) / rho;
      double dl = delta > 0.0 ? delta : 0.0;
      double tau = mean - sqrt(dl);
      if (tau <= x) lc++;
    }
    tcnt[t] = lc;
  }
  __syncthreads();
  if (t == 0) {
    int r = 0;
    for (int i = 0; i < 256; i++) { int c = tcnt[i]; tcnt[i] = r; r += c; }
    sh_S = r;
  }
  __syncthreads();
  {
    int jstar = sh_S - 1;
    if (jstar >= base && jstar < base + 16) {
      double cs = tsum[t], cq = tsq[t], tau = 0.0;
      for (int ii = 0; ii <= jstar - base; ii++) {
        double x = 0.5 * (double)o2f((unsigned)(keys[base + ii] >> 32));
        cs += x; cq += x * x;
        double rho = (double)(base + ii + 1);
        double mean = cs / rho, msq = cq / rho;
        double ss = rho * (msq - mean * mean);
        double delta = (1.0 - ss) / rho;
        double dl = delta > 0.0 ? delta : 0.0;
        tau = mean - sqrt(dl);
      }
      sh_tau = tau;
    }
  }
  __syncthreads();
  const double tau = sh_tau;
  float ps[16], pa[16];
  {
    int lf = 0;
    for (int ii = 0; ii < 16; ii++) {
      int p = base + ii;
      ps[ii] = srow0[p] + srow1[p]; pa[ii] = arow[p];
      double d = 0.5 * (double)ps[ii] - tau;
      if (pa[ii] != 0.f && d > 0.0) lf++;
    }
    tcnt[t] = lf;
  }
  __syncthreads();
  if (t == 0) {
    int r = 0;
    for (int i = 0; i < 256; i++) { int c = tcnt[i]; tcnt[i] = r; r += c; }
    sh_m = r;
  }
  __syncthreads();
  const int m = sh_m;
  const int k0_ = sh_k[0], k1_ = sh_k[1], k2_ = sh_k[2], k3_ = sh_k[3], k4_ = sh_k[4];
  {
    int cex = tcnt[t];
    for (int ii = 0; ii < 16; ii++) {
      int p = base + ii;
      double d = 0.5 * (double)ps[ii] - tau;
      bool av = (pa[ii] != 0.f);
      bool sup = av && (d > 0.0);
      out[b * N + p] = sup ? (float)(d * d) : 0.0f;
      if (!sup) {
        int rank = m + p - cex;
        out[1 * BTc + b * N + p] = (av && rank < k0_) ? 1.f : 0.f;
        out[2 * BTc + b * N + p] = (av && rank < k1_) ? 1.f : 0.f;
        out[3 * BTc + b * N + p] = (av && rank < k2_) ? 1.f : 0.f;
        out[4 * BTc + b * N + p] = (av && rank < k3_) ? 1.f : 0.f;
        out[5 * BTc + b * N + p] = (av && rank < k4_) ? 1.f : 0.f;
      } else {
        cex++;
      }
    }
  }
  for (int r = t; r < m; r += 256) {
    int i = (int)(0xFFFFFFFFu - (unsigned)(keys[r] & 0xFFFFFFFFull));
    out[1 * BTc + b * N + i] = (r < k0_) ? 1.f : 0.f;
    out[2 * BTc + b * N + i] = (r < k1_) ? 1.f : 0.f;
    out[3 * BTc + b * N + i] = (r < k2_) ? 1.f : 0.f;
    out[4 * BTc + b * N + i] = (r < k3_) ? 1.f : 0.f;
    out[5 * BTc + b * N + i] = (r < k4_) ? 1.f : 0.f;
  }
}

extern "C" void kernel_launch(void* const* d_in, const int* in_sizes, int n_in,
                              void* d_out, int out_size, void* d_ws, size_t ws_size,
                              hipStream_t stream) {
  (void)in_sizes; (void)n_in; (void)out_size; (void)ws_size;
  const float* emb  = (const float*)d_in[0];
  const float* attn = (const float*)d_in[1];
  const float* ln_g = (const float*)d_in[2];
  const float* ln_b = (const float*)d_in[3];
  const float* W1   = (const float*)d_in[4];
  const float* b1   = (const float*)d_in[5];
  const float* W2   = (const float*)d_in[6];
  const float* b2   = (const float*)d_in[7];
  float* out = (float*)d_out;
  float* wsf = (float*)d_ws;
  float* mu     = wsf;
  float* rstd   = wsf + BTc;
  float* spart  = wsf + 2 * BTc;             // [2][BTc]
  ushort* w1s   = (ushort*)(wsf + 4 * BTc);  // 3 planes * 1.5 MB

  w1_split_k<<<384, 256, 0, stream>>>(W1, w1s);
  ln_stats_k<<<BTc / 4, 256, 0, stream>>>(emb, attn, mu, rstd);
  gemm_scores_mfma12<<<4096, 256, 0, stream>>>(
      emb, attn, ln_g, ln_b, w1s, b1, W2, b2, mu, rstd, spart);
  entmax_rank_k<<<Bc, 256, 0, stream>>>(spart, spart + BTc, attn, out);
}

// Round 15
// 950.189 us; speedup vs baseline: 1.1702x; 1.0024x over previous
//
#include <hip/hip_runtime.h>
#include <math.h>

#define Bc 32
#define Tc 4096
#define Dc 768
#define Hc 1024
#define BTc (Bc*Tc)
#define PLANE 786432   // 96*1024*8 ushorts per split plane

typedef __bf16 bf16x8 __attribute__((ext_vector_type(8)));
typedef float f32x16 __attribute__((ext_vector_type(16)));

__device__ __forceinline__ float gelu_erf(float x) {
  return 0.5f * x * (1.0f + erff(x * 0.70710678118654752440f));
}
__device__ __forceinline__ unsigned bf16rne(float x) {
  unsigned u = __float_as_uint(x);
  return (u + 0x7FFFu + ((u >> 16) & 1u)) >> 16;
}
// exact 3-way bf16 split: x ~= hi+mid+lo, residual ~2^-27 |x|
__device__ __forceinline__ void split3(float x, unsigned& h, unsigned& m, unsigned& l) {
  h = bf16rne(x);
  float r1 = x - __uint_as_float(h << 16);
  m = bf16rne(r1);
  float r2 = r1 - __uint_as_float(m << 16);
  l = bf16rne(r2);
}
__device__ __forceinline__ unsigned f2o(float f) {
  unsigned b = __float_as_uint(f);
  return (b & 0x80000000u) ? ~b : (b | 0x80000000u);
}
__device__ __forceinline__ float o2f(unsigned o) {
  unsigned b = (o & 0x80000000u) ? (o & 0x7FFFFFFFu) : ~o;
  return __uint_as_float(b);
}

// B-fragment register block: 4 N-tiles of one k-group (12 x 16B = 48 VGPRs)
struct Bfrag { bf16x8 h[4], m[4], l[4]; };

__device__ __forceinline__ void loadB(const ushort* __restrict__ bp0, Bfrag& B) {
  #pragma unroll
  for (int nt = 0; nt < 4; nt++) {
    const ushort* bp = bp0 + nt * 256;     // 32 cols * 8
    B.h[nt] = *(const bf16x8*)(bp);
    B.m[nt] = *(const bf16x8*)(bp + PLANE);
    B.l[nt] = *(const bf16x8*)(bp + 2 * PLANE);
  }
}

// pass-outer / nt-inner; per-acc order (hh,hm,mh,mm,hl,lh) UNCHANGED.
__device__ __forceinline__ void mfma6(bf16x8 a0, bf16x8 a1, bf16x8 a2,
                                      const Bfrag& B, f32x16* acc) {
  #pragma unroll
  for (int nt = 0; nt < 4; nt++)
    acc[nt] = __builtin_amdgcn_mfma_f32_32x32x16_bf16(a0, B.h[nt], acc[nt], 0, 0, 0);
  #pragma unroll
  for (int nt = 0; nt < 4; nt++)
    acc[nt] = __builtin_amdgcn_mfma_f32_32x32x16_bf16(a0, B.m[nt], acc[nt], 0, 0, 0);
  #pragma unroll
  for (int nt = 0; nt < 4; nt++)
    acc[nt] = __builtin_amdgcn_mfma_f32_32x32x16_bf16(a1, B.h[nt], acc[nt], 0, 0, 0);
  #pragma unroll
  for (int nt = 0; nt < 4; nt++)
    acc[nt] = __builtin_amdgcn_mfma_f32_32x32x16_bf16(a1, B.m[nt], acc[nt], 0, 0, 0);
  #pragma unroll
  for (int nt = 0; nt < 4; nt++)
    acc[nt] = __builtin_amdgcn_mfma_f32_32x32x16_bf16(a0, B.l[nt], acc[nt], 0, 0, 0);
  #pragma unroll
  for (int nt = 0; nt < 4; nt++)
    acc[nt] = __builtin_amdgcn_mfma_f32_32x32x16_bf16(a2, B.h[nt], acc[nt], 0, 0, 0);
}

// ---------------- Kernel 0: pre-split W1 into 3 bf16 planes -----------------
__global__ __launch_bounds__(256) void w1_split_k(
    const float* __restrict__ W1, ushort* __restrict__ w1s) {
  int id = blockIdx.x * 256 + threadIdx.x;   // 96*1024 total
  int n = id & 1023, kg = id >> 10;
  unsigned hs[8], ms[8], ls[8];
  #pragma unroll
  for (int j = 0; j < 8; j++) {
    float x = W1[(size_t)(kg * 8 + j) * Hc + n];
    split3(x, hs[j], ms[j], ls[j]);
  }
  size_t o = ((size_t)kg * 1024 + n) * 8;
  int4 ph, pm, pl;
  ph.x = (int)(hs[0] | (hs[1] << 16)); ph.y = (int)(hs[2] | (hs[3] << 16));
  ph.z = (int)(hs[4] | (hs[5] << 16)); ph.w = (int)(hs[6] | (hs[7] << 16));
  pm.x = (int)(ms[0] | (ms[1] << 16)); pm.y = (int)(ms[2] | (ms[3] << 16));
  pm.z = (int)(ms[4] | (ms[5] << 16)); pm.w = (int)(ms[6] | (ms[7] << 16));
  pl.x = (int)(ls[0] | (ls[1] << 16)); pl.y = (int)(ls[2] | (ls[3] << 16));
  pl.z = (int)(ls[4] | (ls[5] << 16)); pl.w = (int)(ls[6] | (ls[7] << 16));
  *(int4*)(w1s + o)             = ph;
  *(int4*)(w1s + o + PLANE)     = pm;
  *(int4*)(w1s + o + 2 * PLANE) = pl;
}

// ---------------- Kernel 1: masked LayerNorm stats (mu, rstd per row) -------
__global__ __launch_bounds__(256) void ln_stats_k(
    const float* __restrict__ emb, const float* __restrict__ attn,
    float* __restrict__ mu, float* __restrict__ rstd) {
  int row = blockIdx.x * 4 + (threadIdx.x >> 6);
  int lane = threadIdx.x & 63;
  float a = attn[row];
  const float4* e = (const float4*)(emb + (size_t)row * Dc);
  float4 v0 = e[lane], v1 = e[lane + 64], v2 = e[lane + 128];
  float x[12] = {v0.x*a, v0.y*a, v0.z*a, v0.w*a,
                 v1.x*a, v1.y*a, v1.z*a, v1.w*a,
                 v2.x*a, v2.y*a, v2.z*a, v2.w*a};
  float s = 0.f;
  #pragma unroll
  for (int i = 0; i < 12; i++) s += x[i];
  #pragma unroll
  for (int o = 32; o; o >>= 1) s += __shfl_xor(s, o);
  float m = s / 768.0f;
  float q = 0.f;
  #pragma unroll
  for (int i = 0; i < 12; i++) { float d = x[i] - m; q += d * d; }
  #pragma unroll
  for (int o = 32; o; o >>= 1) q += __shfl_xor(q, o);
  float var = q / 768.0f;
  if (lane == 0) { mu[row] = m; rstd[row] = 1.0f / sqrtf(var + 1e-5f); }
}

// ---- Kernel 2: r14 structure + BK=96 + setprio(1) around MFMA cluster. ----
// Block 64 rows x 512 cols (XCD-pinned H-half), 4 waves, wave = 64x128
// (2 rt x 4 nt, acc[8]=128 AGPR), 2 blocks/CU (LDS 79KB x2 = 158 <= 160KB).
// 8 K-iters x 288 MFMAs between barriers. Flattened per-lane kgg order
// {12i+2kh+lkg}: scores BIT-IDENTICAL to r14/r10. T5 setprio: 2 blocks/CU
// give wave role diversity (one MFMAs while other stages) -> arbitration pays.
__global__ __launch_bounds__(256, 2) void gemm_scores_mfma13(
    const float* __restrict__ emb, const float* __restrict__ attn,
    const float* __restrict__ ln_g, const float* __restrict__ ln_b,
    const ushort* __restrict__ w1s, const float* __restrict__ b1,
    const float* __restrict__ W2, const float* __restrict__ b2,
    const float* __restrict__ mu, const float* __restrict__ rstd,
    float* __restrict__ spart) {
  __shared__ int4 Abuf[2][3][12][64];   // 72 KB: [buf][split][kg][row] 16B
  __shared__ float gls[768], bls[768];  // 6 KB
  __shared__ float red[4][64];          // 1 KB
  const int id = blockIdx.x;
  const int xcd = id & 7;               // dispatch round-robins XCDs [m09]
  const int y = xcd & 1;                // XCD parity -> H-half (L2 pinning)
  const int xg = (id >> 3) * 4 + (xcd >> 1);   // 0..2047
  const int base = xg * 64;
  if (attn[base] == 0.0f) return;       // attn is a prefix mask
  const int hbase = y * 512;
  const int t = threadIdx.x;
  const int lane = t & 63;
  const int lrow = lane & 31;
  const int lkg = lane >> 5;
  const int w = t >> 6;                 // wave id = 128-col group 0..3

  if (t < 192) {
    *(float4*)&gls[t * 4] = *(const float4*)&ln_g[t * 4];
    *(float4*)&bls[t * 4] = *(const float4*)&ln_b[t * 4];
  }
  // staging identity: 256 threads cover 64 rows x 12 kg (3 chunks each);
  // srow = lane -> wave-linear b128 writes, conflict-free (r10 pattern).
  const int srow = t & 63;
  const int sci = t >> 6;               // 0..3; stages kg = sci, sci+4, sci+8
  const float la  = attn[base + srow];
  const float lmu = mu[base + srow];
  const float lrs = rstd[base + srow];
  const float* erow = emb + (size_t)(base + srow) * Dc;

  f32x16 acc[8];                        // [rt][nt]
  #pragma unroll
  for (int nt = 0; nt < 8; nt++)
    #pragma unroll
    for (int r = 0; r < 16; r++) acc[nt][r] = 0.f;

  __syncthreads();  // gls/bls visible
  // ---- prologue: stage k0=0..95 into buf 0 (3 x 8 elems/thread) ----
  #pragma unroll
  for (int ci = 0; ci < 3; ci++) {
    const int kg = sci + 4 * ci;
    const int ko = kg * 8;
    float4 e0 = *(const float4*)(erow + ko);
    float4 e1 = *(const float4*)(erow + ko + 4);
    float4 g0 = *(const float4*)&gls[ko];
    float4 g1 = *(const float4*)&gls[ko + 4];
    float4 q0 = *(const float4*)&bls[ko];
    float4 q1 = *(const float4*)&bls[ko + 4];
    float xs[8] = {e0.x,e0.y,e0.z,e0.w,e1.x,e1.y,e1.z,e1.w};
    float gs[8] = {g0.x,g0.y,g0.z,g0.w,g1.x,g1.y,g1.z,g1.w};
    float bs[8] = {q0.x,q0.y,q0.z,q0.w,q1.x,q1.y,q1.z,q1.w};
    unsigned hh[8], hm[8], hl[8];
    #pragma unroll
    for (int e = 0; e < 8; e++) {
      float xn = (xs[e] * la - lmu) * lrs * gs[e] + bs[e];
      split3(xn, hh[e], hm[e], hl[e]);
    }
    int4 ph, pm, pl;
    ph.x = (int)(hh[0] | (hh[1] << 16)); ph.y = (int)(hh[2] | (hh[3] << 16));
    ph.z = (int)(hh[4] | (hh[5] << 16)); ph.w = (int)(hh[6] | (hh[7] << 16));
    pm.x = (int)(hm[0] | (hm[1] << 16)); pm.y = (int)(hm[2] | (hm[3] << 16));
    pm.z = (int)(hm[4] | (hm[5] << 16)); pm.w = (int)(hm[6] | (hm[7] << 16));
    pl.x = (int)(hl[0] | (hl[1] << 16)); pl.y = (int)(hl[2] | (hl[3] << 16));
    pl.z = (int)(hl[4] | (hl[5] << 16)); pl.w = (int)(hl[6] | (hl[7] << 16));
    Abuf[0][0][kg][srow] = ph;
    Abuf[0][1][kg][srow] = pm;
    Abuf[0][2][kg][srow] = pl;
  }
  __syncthreads();

  // per-lane B base: col = hbase + w*128 + nt*32 + lrow
  const ushort* wbase = w1s + ((size_t)hbase + w * 128 + lrow) * 8;

  #pragma unroll 1
  for (int i = 0; i < 8; i++) {
    const int p = i & 1;
    const bool more = (i < 7);
    __builtin_amdgcn_s_setprio(1);
    #pragma unroll
    for (int kh = 0; kh < 6; kh++) {
      const int kg = kh * 2 + lkg;
      bf16x8 a00 = *(const bf16x8*)&Abuf[p][0][kg][lrow];        // rt=0
      bf16x8 a01 = *(const bf16x8*)&Abuf[p][1][kg][lrow];
      bf16x8 a02 = *(const bf16x8*)&Abuf[p][2][kg][lrow];
      bf16x8 a10 = *(const bf16x8*)&Abuf[p][0][kg][32 + lrow];   // rt=1
      bf16x8 a11 = *(const bf16x8*)&Abuf[p][1][kg][32 + lrow];
      bf16x8 a12 = *(const bf16x8*)&Abuf[p][2][kg][32 + lrow];
      Bfrag B;
      loadB(wbase + (size_t)(i * 12 + kg) * 8192, B);
      mfma6(a00, a01, a02, B, acc);       // rows 0-31
      mfma6(a10, a11, a12, B, acc + 4);   // rows 32-63 (B reused from regs)
    }
    __builtin_amdgcn_s_setprio(0);
    if (more) {
      #pragma unroll
      for (int ci = 0; ci < 3; ci++) {
        const int kg = sci + 4 * ci;
        const int ko = (i + 1) * 96 + kg * 8;
        float4 e0 = *(const float4*)(erow + ko);
        float4 e1 = *(const float4*)(erow + ko + 4);
        float4 g0 = *(const float4*)&gls[ko];
        float4 g1 = *(const float4*)&gls[ko + 4];
        float4 q0 = *(const float4*)&bls[ko];
        float4 q1 = *(const float4*)&bls[ko + 4];
        float xs[8] = {e0.x,e0.y,e0.z,e0.w,e1.x,e1.y,e1.z,e1.w};
        float gs[8] = {g0.x,g0.y,g0.z,g0.w,g1.x,g1.y,g1.z,g1.w};
        float bs[8] = {q0.x,q0.y,q0.z,q0.w,q1.x,q1.y,q1.z,q1.w};
        unsigned hh[8], hm[8], hl[8];
        #pragma unroll
        for (int e = 0; e < 8; e++) {
          float xn = (xs[e] * la - lmu) * lrs * gs[e] + bs[e];
          split3(xn, hh[e], hm[e], hl[e]);
        }
        int4 ph, pm, pl;
        ph.x = (int)(hh[0] | (hh[1] << 16)); ph.y = (int)(hh[2] | (hh[3] << 16));
        ph.z = (int)(hh[4] | (hh[5] << 16)); ph.w = (int)(hh[6] | (hh[7] << 16));
        pm.x = (int)(hm[0] | (hm[1] << 16)); pm.y = (int)(hm[2] | (hm[3] << 16));
        pm.z = (int)(hm[4] | (hm[5] << 16)); pm.w = (int)(hm[6] | (hm[7] << 16));
        pl.x = (int)(hl[0] | (hl[1] << 16)); pl.y = (int)(hl[2] | (hl[3] << 16));
        pl.z = (int)(hl[4] | (hl[5] << 16)); pl.w = (int)(hl[6] | (hl[7] << 16));
        Abuf[p ^ 1][0][kg][srow] = ph;
        Abuf[p ^ 1][1][kg][srow] = pm;
        Abuf[p ^ 1][2][kg][srow] = pl;
      }
    }
    __syncthreads();
  }

  // ---- epilogue: bias + erf-gelu + W2 dot (identical to round 10) ---------
  #pragma unroll
  for (int rt = 0; rt < 2; rt++) {
    float sacc[16];
    #pragma unroll
    for (int r = 0; r < 16; r++) sacc[r] = 0.f;
    #pragma unroll
    for (int nt = 0; nt < 4; nt++) {
      const int col = hbase + w * 128 + nt * 32 + lrow;
      const float b1v = b1[col];
      const float w2v = W2[col];
      #pragma unroll
      for (int r = 0; r < 16; r++)
        sacc[r] += gelu_erf(acc[rt * 4 + nt][r] + b1v) * w2v;
    }
    #pragma unroll
    for (int r = 0; r < 16; r++) {
      float v = sacc[r];
      v += __shfl_xor(v, 1);  v += __shfl_xor(v, 2);  v += __shfl_xor(v, 4);
      v += __shfl_xor(v, 8);  v += __shfl_xor(v, 16);
      if (lrow == 0) {
        int row = rt * 32 + (r & 3) + 8 * (r >> 2) + 4 * lkg;
        red[w][row] = v;
      }
    }
  }
  __syncthreads();
  if (t < 64) {
    float v = red[0][t] + red[1][t] + red[2][t] + red[3][t];
    if (y == 0) v += b2[0];
    spart[y * BTc + base + t] = v;
  }
}

// ---- Kernel 3: 1.5-entmax (f64 tau), exact stable ranking, h-mask writes ---
__global__ __launch_bounds__(256) void entmax_rank_k(
    const float* __restrict__ sp0, const float* __restrict__ sp1,
    const float* __restrict__ attn, float* __restrict__ out) {
  const int N = 4096;
  __shared__ unsigned long long keys[4096];
  __shared__ double tsum[256], tsq[256];
  __shared__ int tcnt[256];
  __shared__ float sred[4];
  __shared__ double sh_tau;
  __shared__ int sh_S, sh_m, sh_k[5];
  const int b = blockIdx.x;
  const int t = threadIdx.x;
  const float* srow0 = sp0 + b * N;
  const float* srow1 = sp1 + b * N;
  const float* arow = attn + b * N;
  float teff_l = 0.f;
  for (int i = t; i < N; i += 256) {
    float a = arow[i];
    float s = srow0[i] + srow1[i];
    float xe = (a == 0.f) ? -1e9f : s;
    teff_l += a;
    keys[i] = ((unsigned long long)f2o(xe) << 32) |
              (unsigned long long)(0xFFFFFFFFu - (unsigned)i);
  }
  #pragma unroll
  for (int o = 32; o; o >>= 1) teff_l += __shfl_xor(teff_l, o);
  if ((t & 63) == 0) sred[t >> 6] = teff_l;
  __syncthreads();
  if (t == 0) {
    float te = sred[0] + sred[1] + sred[2] + sred[3];
    const float rh[5] = {0.1f, 0.3f, 0.5f, 0.7f, 0.9f};
    for (int r = 0; r < 5; r++) {
      int ki = (int)floorf(rh[r] * te);   // must be f32 math
      sh_k[r] = ki < 1 ? 1 : ki;
    }
  }
  for (int kk = 2; kk <= N; kk <<= 1) {
    for (int j = kk >> 1; j > 0; j >>= 1) {
      __syncthreads();
      for (int idx = t; idx < N / 2; idx += 256) {
        int i = 2 * idx - (idx & (j - 1));
        int l = i | j;
        unsigned long long A = keys[i], Bv = keys[l];
        bool up = ((i & kk) == 0);
        if (up ? (A < Bv) : (A > Bv)) { keys[i] = Bv; keys[l] = A; }
      }
    }
  }
  __syncthreads();
  const int base = t * 16;
  {
    double ls = 0, lq = 0;
    for (int ii = 0; ii < 16; ii++) {
      double x = 0.5 * (double)o2f((unsigned)(keys[base + ii] >> 32));
      ls += x; lq += x * x;
    }
    tsum[t] = ls; tsq[t] = lq;
  }
  __syncthreads();
  if (t == 0) {
    double rs = 0, rq = 0;
    for (int i = 0; i < 256; i++) {
      double a = tsum[i], c = tsq[i];
      tsum[i] = rs; tsq[i] = rq; rs += a; rq += c;
    }
  }
  __syncthreads();
  {
    double cs = tsum[t], cq = tsq[t];
    int lc = 0;
    for (int ii = 0; ii < 16; ii++) {
      double x = 0.5 * (double)o2f((unsigned)(keys[base + ii] >> 32));
      cs += x; cq += x * x;
      double rho = (double)(base + ii + 1);
      double mean = cs / rho, msq = cq / rho;
      double ss = rho * (msq - mean * mean);
      double delta = (1.0 - ss) / rho;
      double dl = delta > 0.0 ? delta : 0.0;
      double tau = mean - sqrt(dl);
      if (tau <= x) lc++;
    }
    tcnt[t] = lc;
  }
  __syncthreads();
  if (t == 0) {
    int r = 0;
    for (int i = 0; i < 256; i++) { int c = tcnt[i]; tcnt[i] = r; r += c; }
    sh_S = r;
  }
  __syncthreads();
  {
    int jstar = sh_S - 1;
    if (jstar >= base && jstar < base + 16) {
      double cs = tsum[t], cq = tsq[t], tau = 0.0;
      for (int ii = 0; ii <= jstar - base; ii++) {
        double x = 0.5 * (double)o2f((unsigned)(keys[base + ii] >> 32));
        cs += x; cq += x * x;
        double rho = (double)(base + ii + 1);
        double mean = cs / rho, msq = cq / rho;
        double ss = rho * (msq - mean * mean);
        double delta = (1.0 - ss) / rho;
        double dl = delta > 0.0 ? delta : 0.0;
        tau = mean - sqrt(dl);
      }
      sh_tau = tau;
    }
  }
  __syncthreads();
  const double tau = sh_tau;
  float ps[16], pa[16];
  {
    int lf = 0;
    for (int ii = 0; ii < 16; ii++) {
      int p = base + ii;
      ps[ii] = srow0[p] + srow1[p]; pa[ii] = arow[p];
      double d = 0.5 * (double)ps[ii] - tau;
      if (pa[ii] != 0.f && d > 0.0) lf++;
    }
    tcnt[t] = lf;
  }
  __syncthreads();
  if (t == 0) {
    int r = 0;
    for (int i = 0; i < 256; i++) { int c = tcnt[i]; tcnt[i] = r; r += c; }
    sh_m = r;
  }
  __syncthreads();
  const int m = sh_m;
  const int k0_ = sh_k[0], k1_ = sh_k[1], k2_ = sh_k[2], k3_ = sh_k[3], k4_ = sh_k[4];
  {
    int cex = tcnt[t];
    for (int ii = 0; ii < 16; ii++) {
      int p = base + ii;
      double d = 0.5 * (double)ps[ii] - tau;
      bool av = (pa[ii] != 0.f);
      bool sup = av && (d > 0.0);
      out[b * N + p] = sup ? (float)(d * d) : 0.0f;
      if (!sup) {
        int rank = m + p - cex;
        out[1 * BTc + b * N + p] = (av && rank < k0_) ? 1.f : 0.f;
        out[2 * BTc + b * N + p] = (av && rank < k1_) ? 1.f : 0.f;
        out[3 * BTc + b * N + p] = (av && rank < k2_) ? 1.f : 0.f;
        out[4 * BTc + b * N + p] = (av && rank < k3_) ? 1.f : 0.f;
        out[5 * BTc + b * N + p] = (av && rank < k4_) ? 1.f : 0.f;
      } else {
        cex++;
      }
    }
  }
  for (int r = t; r < m; r += 256) {
    int i = (int)(0xFFFFFFFFu - (unsigned)(keys[r] & 0xFFFFFFFFull));
    out[1 * BTc + b * N + i] = (r < k0_) ? 1.f : 0.f;
    out[2 * BTc + b * N + i] = (r < k1_) ? 1.f : 0.f;
    out[3 * BTc + b * N + i] = (r < k2_) ? 1.f : 0.f;
    out[4 * BTc + b * N + i] = (r < k3_) ? 1.f : 0.f;
    out[5 * BTc + b * N + i] = (r < k4_) ? 1.f : 0.f;
  }
}

extern "C" void kernel_launch(void* const* d_in, const int* in_sizes, int n_in,
                              void* d_out, int out_size, void* d_ws, size_t ws_size,
                              hipStream_t stream) {
  (void)in_sizes; (void)n_in; (void)out_size; (void)ws_size;
  const float* emb  = (const float*)d_in[0];
  const float* attn = (const float*)d_in[1];
  const float* ln_g = (const float*)d_in[2];
  const float* ln_b = (const float*)d_in[3];
  const float* W1   = (const float*)d_in[4];
  const float* b1   = (const float*)d_in[5];
  const float* W2   = (const float*)d_in[6];
  const float* b2   = (const float*)d_in[7];
  float* out = (float*)d_out;
  float* wsf = (float*)d_ws;
  float* mu     = wsf;
  float* rstd   = wsf + BTc;
  float* spart  = wsf + 2 * BTc;             // [2][BTc]
  ushort* w1s   = (ushort*)(wsf + 4 * BTc);  // 3 planes * 1.5 MB

  w1_split_k<<<384, 256, 0, stream>>>(W1, w1s);
  ln_stats_k<<<BTc / 4, 256, 0, stream>>>(emb, attn, mu, rstd);
  gemm_scores_mfma13<<<4096, 256, 0, stream>>>(
      emb, attn, ln_g, ln_b, w1s, b1, W2, b2, mu, rstd, spart);
  entmax_rank_k<<<Bc, 256, 0, stream>>>(spart, spart + BTc, attn, out);
}